// Round 1
// 245.533 us; speedup vs baseline: 1.1707x; 1.1707x over previous
//
#include <hip/hip_runtime.h>
#include <math.h>

// ---- compile-time tables for the solid-harmonics recurrence ----
constexpr float C00f = 0.28209479177387814f;  // 1/sqrt(4*pi)

// AL[l] = -sqrt((2l+1)/(2l))
constexpr float AL[7] = {0.f,
  -1.22474487139158905f, -1.11803398874989485f, -1.08012344973464354f,
  -1.06066017177982121f, -1.04880884817015154f, -1.04083299973306640f};

// AINV[l][m] = 1/A(l,m), A(l,m)=sqrt((l^2-m^2)/((2l-1)(2l+1))), m<l
constexpr float AINV[7][7] = {
  {0,0,0,0,0,0,0},
  {1.73205080756887729f,0,0,0,0,0,0},
  {1.93649167310370852f,2.23606797749978969f,0,0,0,0,0},
  {1.97202659436653873f,2.09165006633518887f,2.64575131106459059f,0,0,0,0},
  {1.98431348329844304f,2.04939015319191986f,2.29128784747791999f,3.0f,0,0,0},
  {1.98997487421323993f,2.03100960115899020f,2.17124068443428311f,2.48746859276654987f,3.31662479035539985f,0,0},
  {1.99304345718356630f,2.02131499000000000f,2.11394180000000000f,2.30136840000000000f,2.67394840000000000f,3.60555127546398912f,0}
};

// APV[l][m] = A(l-1,m), valid for m <= l-2
constexpr float APV[7][7] = {
  {0,0,0,0,0,0,0},
  {0,0,0,0,0,0,0},
  {0.57735026918962576f,0,0,0,0,0,0},
  {0.51639777949432225f,0.44721359549995794f,0,0,0,0,0},
  {0.50709255283710986f,0.47809144373375745f,0.37796447300922722f,0,0,0,0},
  {0.50395263067896967f,0.48795003647426655f,0.43643578047198484f,0.33333333333333333f,0,0,0},
  {0.50251890762960643f,0.49236596391733095f,0.46056618647183828f,0.40201512610368484f,0.30151134457776363f,0,0}
};

// ---- K0: zero the 294-float c accumulator in workspace (ws is poisoned 0xAA) ----
__global__ void k_zero(float* __restrict__ cg) {
  int t = blockIdx.x * 256 + threadIdx.x;
  if (t < 294) cg[t] = 0.f;
}

// 32-lane reduction (stays inside a half-wave -> ds_swizzle only, 5-deep chain)
__device__ __forceinline__ void red32_acc(float v, float* dst, int li) {
  v += __shfl_xor(v,  1, 32);
  v += __shfl_xor(v,  2, 32);
  v += __shfl_xor(v,  4, 32);
  v += __shfl_xor(v,  8, 32);
  v += __shfl_xor(v, 16, 32);
  if (li == 0) atomicAdd(dst, v);
}

// ---- K1: c[a,row,col] = sum_j f[a,j] * Ypacked[row,col,j]
// Half-wave split: lanes 0-31 handle a in {0,1,2}, lanes 32-63 handle a in {3,4,5}
// of the SAME 32 atoms. 2x waves/SIMD vs one-thread-per-atom; shuffles never
// cross the 32-lane boundary.
__global__ __launch_bounds__(256) void k_accum_c(const float* __restrict__ xyz,
                                                 float* __restrict__ cg, int n) {
  __shared__ float cl[294];
  for (int i = threadIdx.x; i < 294; i += 256) cl[i] = 0.f;
  __syncthreads();
  int lane = threadIdx.x & 63;
  int wv   = threadIdx.x >> 6;      // wave in block: 0..3
  int li   = lane & 31;             // lane within half
  int half = lane >> 5;             // 0 -> a base 0, 1 -> a base 3
  int atom = blockIdx.x * 128 + wv * 32 + li;
  int ji = (atom < n) ? atom : 0;
  float x = xyz[3*ji+0], y = xyz[3*ji+1], z = xyz[3*ji+2];
  float r2 = x*x + y*y + z*z;
  float d  = sqrtf(r2);
  float tcut = 1.f - d * (1.f/6.f);
  float r = (d < 6.f && atom < n) ? tcut*tcut : 0.f;   // invalid lanes -> 0
  // f[a] = r * r2^a for this half's three a's
  float r2c  = r2*r2*r2;
  float base = half ? (r*r2c) : r;
  float fa[3];
  fa[0] = base; fa[1] = base*r2; fa[2] = fa[1]*r2;
  int abase = 3*half;

  float vr[2][7], vi[2][7];
  vr[0][0] = C00f; vi[0][0] = 0.f;
  #pragma unroll
  for (int l = 0; l <= 6; ++l) {
    const int cur = l & 1, prv = cur ^ 1;
    if (l > 0) {
      #pragma unroll
      for (int m = 0; m + 2 <= l; ++m) {      // two-term recurrence (prev2 in-place)
        float ai = AINV[l][m], ap = APV[l][m];
        vr[cur][m] = (z*vr[prv][m] - ap*r2*vr[cur][m]) * ai;
        vi[cur][m] = (z*vi[prv][m] - ap*r2*vi[cur][m]) * ai;
      }
      { float ai = AINV[l][l-1];              // one-term, m = l-1
        float vpr = vr[prv][l-1], vpi = vi[prv][l-1];
        vr[cur][l-1] = z*vpr*ai;
        vi[cur][l-1] = z*vpi*ai;
        vr[cur][l] = AL[l]*(x*vpr - y*vpi);   // diagonal m = l
        vi[cur][l] = AL[l]*(x*vpi + y*vpr); }
    }
    // re(l,m) -> packed (l, l-m); im(l,m>=1) -> packed (m-1, l)
    #pragma unroll
    for (int m = 0; m <= l; ++m) {
      int idx_re = l*7 + (l - m);
      #pragma unroll
      for (int i = 0; i < 3; ++i)
        red32_acc(fa[i]*vr[cur][m], &cl[(abase+i)*49 + idx_re], li);
      if (m >= 1) {
        int idx_im = (m-1)*7 + l;
        #pragma unroll
        for (int i = 0; i < 3; ++i)
          red32_acc(fa[i]*vi[cur][m], &cl[(abase+i)*49 + idx_im], li);
      }
    }
  }
  __syncthreads();
  for (int i = threadIdx.x; i < 294; i += 256) atomicAdd(&cg[i], cl[i]);
}

// ---- K3: dp[l,a,b,j,k] (+ p[l,a,b] folded into block 0) ----
// One thread per (atom j, component k), tid = 3j+k.
// Epilogue exploits dp symmetry in (a,b): compute 21, store 36, and factors
// the direction term pk/d out of the radial-derivative part.
__global__ __launch_bounds__(256) void k_dp(const float* __restrict__ xyz,
                                            const float* __restrict__ cg,
                                            float* __restrict__ out, int n3) {
  __shared__ float cs[294];
  for (int i = threadIdx.x; i < 294; i += 256) cs[i] = cg[i];
  __syncthreads();

  // folded k_p: p[l,a,b] = Yr/Yi masked contraction of c*c (252 outputs)
  if (blockIdx.x == 0 && threadIdx.x < 252) {
    int t = threadIdx.x;
    int pl = t / 36;
    int rem = t - 36*pl;
    int pa = rem / 6;
    int pb = rem - 6*pa;
    const float* ca = cs + pa*49;
    const float* cb = cs + pb*49;
    float s = 0.f;
    for (int mc = 0; mc <= pl; ++mc) {
      float wq = (mc == pl) ? 1.f : 2.f;
      s += wq * ca[pl*7+mc] * cb[pl*7+mc];
    }
    for (int rr = 0; rr < pl; ++rr)
      s += 2.f * ca[rr*7+pl] * cb[rr*7+pl];
    out[t] = s;
  }

  int tid = blockIdx.x * 256 + threadIdx.x;
  if (tid >= n3) return;
  int j = tid / 3;
  int k = tid - 3*j;
  float x = xyz[3*j+0], y = xyz[3*j+1], z = xyz[3*j+2];
  float ex = (k == 0) ? 1.f : 0.f;
  float ey = (k == 1) ? 1.f : 0.f;
  float ez = (k == 2) ? 1.f : 0.f;
  float pk = ex*x + ey*y + ez*z;       // xyz[k]
  float r2 = x*x + y*y + z*z;
  float d  = sqrtf(r2);
  float invd = (d > 0.f) ? 1.f/d : 0.f;
  bool inside = d < 6.f;
  float tcut = 1.f - d*(1.f/6.f);
  float r  = inside ? tcut*tcut : 0.f;
  float dr = inside ? (-1.f/3.f)*tcut : 0.f;
  float f[6], dfr[6];                  // f[a], dfr[a] = d f[a] / d d
  { float dp = 1.f;
    #pragma unroll
    for (int a = 0; a < 6; ++a) {
      f[a]   = r*dp;
      dfr[a] = dp*(dr + (2.f*a)*r*invd);
      dp *= r2;
    } }
  float w = pk * invd;                 // direction factor xyz[k]/d
  float* outdp = out + 252;

  // value + d/dk recurrence, two rows ping-pong (row l-2 overwritten in place)
  float vr[2][7], vi[2][7], gr[2][7], gi[2][7];
  vr[0][0] = C00f; vi[0][0] = 0.f; gr[0][0] = 0.f; gi[0][0] = 0.f;
  #pragma unroll
  for (int l = 0; l <= 6; ++l) {
    const int cur = l & 1, prv = cur ^ 1;
    if (l > 0) {
      #pragma unroll
      for (int m = 0; m + 2 <= l; ++m) {
        float ai = AINV[l][m], ap = APV[l][m];
        float ovr = vr[cur][m], ovi = vi[cur][m];   // row l-2 (read before overwrite)
        float ogr = gr[cur][m], ogi = gi[cur][m];
        vr[cur][m] = (z*vr[prv][m] - ap*r2*ovr) * ai;
        gr[cur][m] = (ez*vr[prv][m] + z*gr[prv][m] - ap*(2.f*pk*ovr + r2*ogr)) * ai;
        vi[cur][m] = (z*vi[prv][m] - ap*r2*ovi) * ai;
        gi[cur][m] = (ez*vi[prv][m] + z*gi[prv][m] - ap*(2.f*pk*ovi + r2*ogi)) * ai;
      }
      { float ai  = AINV[l][l-1];
        float vpr = vr[prv][l-1], vpi = vi[prv][l-1];
        float gpr = gr[prv][l-1], gpi = gi[prv][l-1];
        vr[cur][l-1] = z*vpr*ai;
        gr[cur][l-1] = (ez*vpr + z*gpr)*ai;
        vi[cur][l-1] = z*vpi*ai;
        gi[cur][l-1] = (ez*vpi + z*gpi)*ai;
        vr[cur][l] = AL[l]*(x*vpr - y*vpi);
        gr[cur][l] = AL[l]*(ex*vpr + x*gpr - ey*vpi - y*gpi);
        vi[cur][l] = AL[l]*(x*vpi + y*vpr);
        gi[cur][l] = AL[l]*(ex*vpi + x*gpi + ey*vpr + y*gpr); }
    }
    // G[b] = masked Y*c for degree l (k-independent); Hh[b] = same with dY/dk
    float G[6]  = {0,0,0,0,0,0};
    float Hh[6] = {0,0,0,0,0,0};
    #pragma unroll
    for (int m = 0; m <= l; ++m) {
      float wm = (m == 0) ? 1.f : 2.f;           // packed diagonal is m=0
      float wv = wm*vr[cur][m], wg = wm*gr[cur][m];
      int base = l*7 + (l - m);
      #pragma unroll
      for (int b = 0; b < 6; ++b) { float cc = cs[b*49 + base]; G[b] += wv*cc; Hh[b] += wg*cc; }
      if (m >= 1) {
        float wv2 = 2.f*vi[cur][m], wg2 = 2.f*gi[cur][m];
        int base2 = (m-1)*7 + l;
        #pragma unroll
        for (int b = 0; b < 6; ++b) { float cc = cs[b*49 + base2]; G[b] += wv2*cc; Hh[b] += wg2*cc; }
      }
    }
    // dp[l,a,b] = (dfr[a]G[b]+dfr[b]G[a])*w + f[a]H[b]+f[b]H[a]  (symmetric a<->b)
    #pragma unroll
    for (int a = 0; a < 6; ++a) {
      #pragma unroll
      for (int b = a; b < 6; ++b) {
        float U = dfr[a]*G[b] + dfr[b]*G[a];
        float V = f[a]*Hh[b] + f[b]*Hh[a];
        float val = U*w + V;
        outdp[(size_t)(l*36 + a*6 + b) * (size_t)n3 + (size_t)tid] = val;
        if (b > a)
          outdp[(size_t)(l*36 + b*6 + a) * (size_t)n3 + (size_t)tid] = val;
      }
    }
  }
}

extern "C" void kernel_launch(void* const* d_in, const int* in_sizes, int n_in,
                              void* d_out, int out_size, void* d_ws, size_t ws_size,
                              hipStream_t stream) {
  const float* xyz = (const float*)d_in[0];
  float* out = (float*)d_out;
  float* cg  = (float*)d_ws;      // 294 floats of scratch for c[a,row,col]
  int n3 = in_sizes[0];           // N*3 = 196608
  int n  = n3 / 3;                // N   = 65536

  k_zero   <<<dim3(2),               dim3(256), 0, stream>>>(cg);
  k_accum_c<<<dim3((n + 127)/128),   dim3(256), 0, stream>>>(xyz, cg, n);
  k_dp     <<<dim3((n3 + 255)/256),  dim3(256), 0, stream>>>(xyz, cg, out, n3);
}